// Round 7
// baseline (298.499 us; speedup 1.0000x reference)
//
#include <hip/hip_runtime.h>
#include <hip/hip_bf16.h>

typedef unsigned short u16;
typedef __bf16 bf16x8 __attribute__((ext_vector_type(8)));
typedef float f32x4 __attribute__((ext_vector_type(4)));
typedef unsigned short u16x4 __attribute__((ext_vector_type(4)));

#define MFMA16(a, b, c) __builtin_amdgcn_mfma_f32_16x16x32_bf16(a, b, c, 0, 0, 0)

#define EMB 1024
#define SEQ 2048
#define NH 16
#define HD 64
#define LOG2E 1.4426950408889634f

// async global->LDS, 16B per lane; LDS dest = wave-uniform base + lane*16
#define GLOAD_LDS16(g, l) __builtin_amdgcn_global_load_lds( \
    (const __attribute__((address_space(1))) unsigned int*)(g), \
    (__attribute__((address_space(3))) unsigned int*)(l), 16, 0, 0)

__device__ __forceinline__ float b2f(u16 u) {
    union { unsigned int i; float f; } v; v.i = ((unsigned int)u) << 16; return v.f;
}
__device__ __forceinline__ u16 f2b(float f) {
    __hip_bfloat16 h = __float2bfloat16(f);
    return *reinterpret_cast<u16*>(&h);
}
__device__ __forceinline__ u16x4 pack4(float a, float b, float c, float d) {
    union { __hip_bfloat162 h2[2]; u16x4 u; } r;
    r.h2[0] = __float22bfloat162_rn(float2{a, b});
    r.h2[1] = __float22bfloat162_rn(float2{c, d});
    return r.u;
}
__device__ __forceinline__ bf16x8 ldfrag(const u16* p) {
    return *reinterpret_cast<const bf16x8*>(p);
}
__device__ __forceinline__ bf16x8 cvt8(const float* p) {
    const float4 a = *reinterpret_cast<const float4*>(p);
    const float4 b = *reinterpret_cast<const float4*>(p + 4);
    union { u16x4 q[2]; bf16x8 v; } r;
    r.q[0] = pack4(a.x, a.y, a.z, a.w);
    r.q[1] = pack4(b.x, b.y, b.z, b.w);
    return r.v;
}
// tanh via hw exp2 + rcp: rel err < 1e-6, safe for |x| < 40
__device__ __forceinline__ float fast_tanh(float x) {
    float t = exp2f(x * (2.0f * LOG2E));
    return 1.0f - 2.0f * __builtin_amdgcn_rcpf(t + 1.0f);
}
__device__ __forceinline__ bf16x8 tanh8(bf16x8 v) {
    union { bf16x8 v; u16 u[8]; } in; in.v = v;
    float o[8];
#pragma unroll
    for (int e = 0; e < 8; e++) o[e] = fast_tanh(b2f(in.u[e]));
    union { u16x4 q[2]; bf16x8 v; } r;
    r.q[0] = pack4(o[0], o[1], o[2], o[3]);
    r.q[1] = pack4(o[4], o[5], o[6], o[7]);
    return r.v;
}

// ---------------------------------------------------------------------------
// fp32 -> bf16 conversion: [x (4096x1024) | Wq | Wk | Wv | Wo] -> ws bf16
// ---------------------------------------------------------------------------
__global__ __launch_bounds__(256) void cvt_all(
        const float* __restrict__ x,  const float* __restrict__ Wq,
        const float* __restrict__ Wk, const float* __restrict__ Wv,
        const float* __restrict__ Wo, u16* __restrict__ dst)
{
    size_t i = ((size_t)blockIdx.x * 256 + threadIdx.x) * 8;
    const float* src; size_t off;
    if (i < 4194304) { src = x; off = i; }
    else {
        size_t j = i - 4194304; int w = (int)(j >> 20); off = j & 1048575;
        src = (w == 0) ? Wq : (w == 1) ? Wk : (w == 2) ? Wv : Wo;
    }
    *(bf16x8*)&dst[i] = cvt8(src + off);
}

// ---------------------------------------------------------------------------
// GEMM: C = A(MxK,bf16) @ W(NxK,bf16)^T + bias(fp32). Tile MI*32 x 128, BK=64.
// SW=1: compute C^T (swap MFMA operands) -> acc regs span contiguous n ->
//       packed u16x4 / float4 epilogue stores (modes 0/1/3).
// SW=0: normal orientation (mode 2: V^T store is already packed along s).
// mode 0: Qa[:,0:64]=Q/8*log2e, Qa[:,64:128]=lam*log2e*tanh(Q) (B,H,S,128)
// mode 1: Ka[:,0:64]=K                                (B,H,S,128) bf16
// mode 2: Vt[b,h,d,s]=V  (transposed)                 (B,H,HD,S)  bf16
// mode 3: out = val fp32 (row-major M x EMB)
// ---------------------------------------------------------------------------
template<int MI, int SW>
__global__ __launch_bounds__(256, 4) void gemm_epi(
        const u16* __restrict__ A,
        const u16* __restrict__ W0, const float* __restrict__ B0,
        const u16* __restrict__ W1, const float* __restrict__ B1,
        const float* __restrict__ lam,
        u16* __restrict__ Qa, u16* __restrict__ Ka, u16* __restrict__ Vt,
        float* __restrict__ out, int modeBase)
{
    const int mode = modeBase + blockIdx.z;
    const u16* W; const float* bias;
    if (blockIdx.z == 0) { W = W0; bias = B0; }
    else                 { W = W1; bias = B1; }

    __shared__ __attribute__((aligned(16))) u16 sA[MI * 32 * 64];
    __shared__ __attribute__((aligned(16))) u16 sB[128 * 64];

    const int t = threadIdx.x;
    const int w = t >> 6, L = t & 63;
    const int wm = w >> 1, wn = w & 1;
    const int lr = L & 15, lq = L >> 4;
    const int wbase = t & 192;                   // wave*64
    const int m0 = blockIdx.y * (MI * 32), n0 = blockIdx.x * 128;

    f32x4 acc[MI][4];
#pragma unroll
    for (int i = 0; i < MI; i++)
#pragma unroll
        for (int j = 0; j < 4; j++) { f32x4 z = {0.f, 0.f, 0.f, 0.f}; acc[i][j] = z; }

    for (int k0 = 0; k0 < EMB; k0 += 64) {
        __syncthreads();
        // stage A: MI*256 chunks of 8 elems (8 chunks/row), col8 = cc ^ (row&7)
#pragma unroll
        for (int q = 0; q < MI; q++) {
            int c = q * 256 + t;
            int row = c >> 3, cc = c & 7;
            int col8 = cc ^ (row & 7);
            GLOAD_LDS16(&A[(size_t)(m0 + row) * EMB + k0 + col8 * 8],
                        &sA[(q * 256 + wbase) * 8]);
        }
        // stage B: 1024 chunks
#pragma unroll
        for (int q = 0; q < 4; q++) {
            int c = q * 256 + t;
            int row = c >> 3, cc = c & 7;
            int col8 = cc ^ (row & 7);
            GLOAD_LDS16(&W[(size_t)(n0 + row) * EMB + k0 + col8 * 8],
                        &sB[(q * 256 + wbase) * 8]);
        }
        __syncthreads();
        // two 32-k sub-chunks; fragments loaded per sub-chunk to bound VGPR
#pragma unroll
        for (int s = 0; s < 2; s++) {
            bf16x8 af[MI], bfr[4];
#pragma unroll
            for (int mi = 0; mi < MI; mi++) {
                int row = wm * (MI * 16) + mi * 16 + lr;
                af[mi] = ldfrag(&sA[(row * 8 + ((s * 4 + lq) ^ (row & 7))) * 8]);
            }
#pragma unroll
            for (int ni = 0; ni < 4; ni++) {
                int row = wn * 64 + ni * 16 + lr;
                bfr[ni] = ldfrag(&sB[(row * 8 + ((s * 4 + lq) ^ (row & 7))) * 8]);
            }
#pragma unroll
            for (int mi = 0; mi < MI; mi++)
#pragma unroll
                for (int ni = 0; ni < 4; ni++) {
                    if constexpr (SW) acc[mi][ni] = MFMA16(bfr[ni], af[mi], acc[mi][ni]);
                    else              acc[mi][ni] = MFMA16(af[mi], bfr[ni], acc[mi][ni]);
                }
        }
    }

    const float lamf = lam[0];
    if constexpr (SW) {
        // C^T: lane -> m = ...+lr (fixed row), regs span n = nb..nb+3 contiguous
#pragma unroll
        for (int mi = 0; mi < MI; mi++)
#pragma unroll
            for (int ni = 0; ni < 4; ni++) {
                int m  = m0 + wm * (MI * 16) + mi * 16 + lr;
                int nb = n0 + wn * 64 + ni * 16 + lq * 4;
                float4 bv4 = *(const float4*)&bias[nb];
                float v0 = acc[mi][ni][0] + bv4.x, v1 = acc[mi][ni][1] + bv4.y;
                float v2 = acc[mi][ni][2] + bv4.z, v3 = acc[mi][ni][3] + bv4.w;
                if (mode == 3) {
                    *(float4*)&out[(size_t)m * EMB + nb] = float4{v0, v1, v2, v3};
                } else {
                    int b = m >> 11, s0 = m & 2047;
                    int h = nb >> 6, d = nb & 63;
                    size_t i128 = ((size_t)(b * NH + h) * SEQ + s0) * 128 + d;
                    if (mode == 0) {
                        const float cs = 0.125f * LOG2E, ct = lamf * LOG2E;
                        *(u16x4*)&Qa[i128] = pack4(v0 * cs, v1 * cs, v2 * cs, v3 * cs);
                        *(u16x4*)&Qa[i128 + 64] =
                            pack4(ct * fast_tanh(v0), ct * fast_tanh(v1),
                                  ct * fast_tanh(v2), ct * fast_tanh(v3));
                    } else {
                        *(u16x4*)&Ka[i128] = pack4(v0, v1, v2, v3);
                    }
                }
            }
    } else {
        // normal: regs span m (s-rows); used for mode 2 (V^T packed along s)
#pragma unroll
        for (int mi = 0; mi < MI; mi++)
#pragma unroll
            for (int ni = 0; ni < 4; ni++) {
                int mb = m0 + wm * (MI * 16) + mi * 16 + lq * 4;
                int n  = n0 + wn * 64 + ni * 16 + lr;
                float bv = bias[n];
                int b = mb >> 11, s0 = mb & 2047;
                int h = n >> 6,  d = n & 63;
                u16x4 pk = pack4(acc[mi][ni][0] + bv, acc[mi][ni][1] + bv,
                                 acc[mi][ni][2] + bv, acc[mi][ni][3] + bv);
                *(u16x4*)&Vt[((size_t)(b * NH + h) * HD + d) * SEQ + s0] = pk;
            }
    }
}

// ---------------------------------------------------------------------------
// U kernel: Ka[:,64:128] = tanh(K) @ J_h^T per (b,h); K read from Ka[:,0:64]
// grid: (S/64, B*H), 256 threads
// ---------------------------------------------------------------------------
__global__ __launch_bounds__(256) void ukern(
        const float* __restrict__ J, u16* __restrict__ Ka)
{
    __shared__ __attribute__((aligned(16))) u16 sJ[64 * 72];
    const int t = threadIdx.x, w = t >> 6, L = t & 63, lr = L & 15, lq = L >> 4;
    const int rt = blockIdx.x, bh = blockIdx.y, h = bh & 15;

#pragma unroll
    for (int i = 0; i < 2; i++) {
        int c = t + 256 * i;
        int row = c >> 3, col = (c & 7) * 8;
        *(bf16x8*)&sJ[row * 72 + col] = cvt8(&J[(size_t)h * 4096 + row * 64 + col]);
    }
    __syncthreads();

    const u16* krow = &Ka[((size_t)bh * SEQ + rt * 64 + w * 16 + lr) * 128];
    bf16x8 a0 = tanh8(ldfrag(krow + lq * 8));
    bf16x8 a1 = tanh8(ldfrag(krow + lq * 8 + 32));
#pragma unroll
    for (int nt = 0; nt < 4; nt++) {
        f32x4 acc = {0.f, 0.f, 0.f, 0.f};
        acc = MFMA16(a0, ldfrag(&sJ[(nt * 16 + lr) * 72 + lq * 8]), acc);
        acc = MFMA16(a1, ldfrag(&sJ[(nt * 16 + lr) * 72 + lq * 8 + 32]), acc);
#pragma unroll
        for (int r = 0; r < 4; r++) {
            int j = rt * 64 + w * 16 + lq * 4 + r;
            Ka[((size_t)bh * SEQ + j) * 128 + 64 + nt * 16 + lr] = f2b(acc[r]);
        }
    }
}

// ---------------------------------------------------------------------------
// Causal flash, S^T formulation, BM=128, BARRIER-FREE: K and V^T fragments
// are loaded directly global(L2)->regs (A-operand layout == row-major rows),
// LDS holds only the wave-private P strip -> zero __syncthreads, waves
// free-run, no vmcnt(0) barrier drain. No-max softmax (scores bounded).
// grid: (256, 2): bh = bx&31 (XCD-local), p = bx>>5; qt = by? 15-p : p
// -> round-robin pair per CU sums to 34 k-tile iters (balanced).
// ---------------------------------------------------------------------------
__global__ __launch_bounds__(256) void flash(
        const u16* __restrict__ Qa, const u16* __restrict__ Ka,
        const u16* __restrict__ Vt, u16* __restrict__ attn)
{
    __shared__ __attribute__((aligned(16))) u16 sP[128 * 72];   // wave-private rows

    const int t = threadIdx.x, w = t >> 6, L = t & 63, lr = L & 15, lq = L >> 4;
    const int bh = blockIdx.x & 31, p = blockIdx.x >> 5;
    const int qt = blockIdx.y ? 15 - p : p;
    const int qm = qt * 128;
    const int i_l = w * 16 + lr;            // lane's q-row within a 64-set
    const u16* Kbase = Ka + (size_t)bh * SEQ * 128;
    const u16* Vbase = Vt + (size_t)bh * HD * SEQ;

    // two Q B-operand sets: set g covers q-rows qm + g*64 + [0,64)
    bf16x8 qf[2][4];
#pragma unroll
    for (int g = 0; g < 2; g++) {
        const u16* qrow = Qa + ((size_t)bh * SEQ + qm + g * 64 + i_l) * 128;
#pragma unroll
        for (int s = 0; s < 4; s++) qf[g][s] = ldfrag(qrow + s * 32 + lq * 8);
    }

    f32x4 Ot[2][4];
#pragma unroll
    for (int g = 0; g < 2; g++)
#pragma unroll
        for (int i = 0; i < 4; i++) { f32x4 z = {0.f, 0.f, 0.f, 0.f}; Ot[g][i] = z; }
    float lsum[2] = {0.f, 0.f};

    const int ktmax = 2 * qt + 1;
    for (int kt = 0; kt <= ktmax; kt++) {
        const int kn = kt * 64;

        // S^T: K A-fragments straight from global (16 rows x 16B, L2-resident)
        f32x4 sc[2][4];
#pragma unroll
        for (int mt = 0; mt < 4; mt++) { f32x4 z = {0.f,0.f,0.f,0.f}; sc[0][mt] = z; sc[1][mt] = z; }
#pragma unroll
        for (int mt = 0; mt < 4; mt++) {
            const u16* krow = Kbase + (size_t)(kn + mt * 16 + lr) * 128 + lq * 8;
#pragma unroll
            for (int s = 0; s < 4; s++) {
                bf16x8 kf = ldfrag(krow + s * 32);
                sc[0][mt] = MFMA16(kf, qf[0][s], sc[0][mt]);
                sc[1][mt] = MFMA16(kf, qf[1][s], sc[1][mt]);
            }
        }
        // causal masks only on the last two k-tiles
        if (kt >= ktmax - 1) {
            const int thr0 = (kt == ktmax) ? -1  : i_l;
            const int thr1 = (kt == ktmax) ? i_l : 63;
#pragma unroll
            for (int mt = 0; mt < 4; mt++)
#pragma unroll
                for (int r = 0; r < 4; r++) {
                    int j = mt * 16 + lq * 4 + r;
                    if (j > thr0) sc[0][mt][r] = -INFINITY;
                    if (j > thr1) sc[1][mt][r] = -INFINITY;
                }
        }
        // no-max softmax: P = exp2(s); per-lane partial sums; P -> wave-private LDS
#pragma unroll
        for (int g = 0; g < 2; g++) {
#pragma unroll
            for (int mt = 0; mt < 4; mt++)
#pragma unroll
                for (int r = 0; r < 4; r++) {
                    float e = exp2f(sc[g][mt][r]);
                    sc[g][mt][r] = e;
                    lsum[g] += e;
                }
#pragma unroll
            for (int mt = 0; mt < 4; mt++)
                *(u16x4*)&sP[(g * 64 + i_l) * 72 + mt * 16 + lq * 4] =
                    pack4(sc[g][mt][0], sc[g][mt][1], sc[g][mt][2], sc[g][mt][3]);
        }
        // O^T += V^T @ P^T: V A-fragments straight from global, P from LDS
#pragma unroll
        for (int s2 = 0; s2 < 2; s2++) {
            bf16x8 pf0 = ldfrag(&sP[(i_l) * 72 + s2 * 32 + lq * 8]);
            bf16x8 pf1 = ldfrag(&sP[(64 + i_l) * 72 + s2 * 32 + lq * 8]);
#pragma unroll
            for (int mt = 0; mt < 4; mt++) {
                bf16x8 vf = ldfrag(Vbase + (size_t)(mt * 16 + lr) * SEQ
                                   + kn + s2 * 32 + lq * 8);
                Ot[0][mt] = MFMA16(vf, pf0, Ot[0][mt]);
                Ot[1][mt] = MFMA16(vf, pf1, Ot[1][mt]);
            }
        }
    }

    const int b = bh >> 4, h = bh & 15;
#pragma unroll
    for (int g = 0; g < 2; g++) {
        float ls = lsum[g];
        ls += __shfl_xor(ls, 16);
        ls += __shfl_xor(ls, 32);
        const float r0 = __builtin_amdgcn_rcpf(ls);
        const float inv = r0 * (2.0f - ls * r0);  // NR refine
        const size_t base = ((size_t)(b * SEQ + qm + g * 64 + i_l)) * EMB + h * HD;
#pragma unroll
        for (int mt = 0; mt < 4; mt++)
            *(u16x4*)&attn[base + mt * 16 + lq * 4] =
                pack4(Ot[g][mt][0] * inv, Ot[g][mt][1] * inv,
                      Ot[g][mt][2] * inv, Ot[g][mt][3] * inv);
    }
}

// ---------------------------------------------------------------------------
extern "C" void kernel_launch(void* const* d_in, const int* in_sizes, int n_in,
                              void* d_out, int out_size, void* d_ws, size_t ws_size,
                              hipStream_t stream)
{
    const float* x   = (const float*)d_in[0];
    const float* Wq  = (const float*)d_in[1];
    const float* bq  = (const float*)d_in[2];
    const float* Wk  = (const float*)d_in[3];
    const float* bk  = (const float*)d_in[4];
    const float* Wv  = (const float*)d_in[5];
    const float* bv  = (const float*)d_in[6];
    const float* Wo  = (const float*)d_in[7];
    const float* bo  = (const float*)d_in[8];
    const float* J   = (const float*)d_in[9];
    const float* lam = (const float*)d_in[10];

    u16* ws  = (u16*)d_ws;
    u16* xb  = ws;                                   // 4096*1024 bf16 (reused as attn)
    u16* Wqb = xb  + (size_t)4096 * 1024;
    u16* Wkb = Wqb + (size_t)1024 * 1024;
    u16* Wvb = Wkb + (size_t)1024 * 1024;
    u16* Wob = Wvb + (size_t)1024 * 1024;
    u16* Qa  = Wob + (size_t)1024 * 1024;            // 32*2048*128
    u16* Ka  = Qa  + (size_t)32 * 2048 * 128;        // 32*2048*128
    u16* Vt  = Ka  + (size_t)32 * 2048 * 128;        // 32*64*2048 (b,h,d,s)
    u16* attn = xb;                                  // alias: xb dead after QKV
    float* dout = (float*)d_out;

    dim3 blk(256);
    // fp32 -> bf16 for x and the four weight matrices
    cvt_all<<<dim3(4096), blk, 0, stream>>>(x, Wq, Wk, Wv, Wo, ws);
    // Q and K projections (swapped-operand epilogue: packed u16x4 stores)
    gemm_epi<4, 1><<<dim3(8, 32, 2), blk, 0, stream>>>(
        xb, Wqb, bq, Wkb, bk, lam, Qa, Ka, Vt, dout, 0);
    // V projection (normal orientation: V^T store packed along s)
    gemm_epi<4, 0><<<dim3(8, 32, 1), blk, 0, stream>>>(
        xb, Wvb, bv, Wvb, bv, lam, Qa, Ka, Vt, dout, 2);
    // Ka[:,64:128] = tanh(K) @ J_h^T
    ukern<<<dim3(32, 32), blk, 0, stream>>>(J, Ka);
    // causal flash attention, BM=128, barrier-free (K/V direct from L2)
    flash<<<dim3(256, 2), blk, 0, stream>>>(Qa, Ka, Vt, attn);
    // output projection (swapped: float4 stores; 64-row tiles -> 512 blocks)
    gemm_epi<2, 1><<<dim3(8, 64, 1), blk, 0, stream>>>(
        attn, Wob, bo, Wob, bo, lam, Qa, Ka, Vt, dout, 3);
}